// Round 2
// baseline (174.161 us; speedup 1.0000x reference)
//
#include <hip/hip_runtime.h>

#define NQ 4
#define NL 2
#define NA 16
#define HDIM 256
#define RPB 128   // rows per block -> 2048 blocks at B=262144

// Generic 1-qubit gate on qubit with mask M. u = {u00r,u00i,u01r,u01i,u10r,u10i,u11r,u11i}
template<int M>
__device__ __forceinline__ void apply_u(float* sr, float* si, const float* u) {
    const float u00r = u[0], u00i = u[1], u01r = u[2], u01i = u[3];
    const float u10r = u[4], u10i = u[5], u11r = u[6], u11i = u[7];
#pragma unroll
    for (int k = 0; k < 16; ++k) {
        if (k & M) continue;
        const int k1 = k | M;
        const float a0r = sr[k],  a0i = si[k];
        const float a1r = sr[k1], a1i = si[k1];
        sr[k]  = u00r*a0r - u00i*a0i + u01r*a1r - u01i*a1i;
        si[k]  = u00r*a0i + u00i*a0r + u01r*a1i + u01i*a1r;
        sr[k1] = u10r*a0r - u10i*a0i + u11r*a1r - u11i*a1i;
        si[k1] = u10r*a0i + u10i*a0r + u11r*a1i + u11i*a1r;
    }
}

template<int MC, int MT>
__device__ __forceinline__ void cnot(float* sr, float* si) {
#pragma unroll
    for (int k = 0; k < 16; ++k) {
        if ((k & MC) && !(k & MT)) {
            const int k1 = k | MT;
            float tr = sr[k]; sr[k] = sr[k1]; sr[k1] = tr;
            float ti = si[k]; si[k] = si[k1]; si[k1] = ti;
        }
    }
}

__global__ __launch_bounds__(256, 4) void qph_kernel(
    const float* __restrict__ h,
    const float* __restrict__ W_embed,
    const float* __restrict__ b_embed,
    const float* __restrict__ q_weights,
    const float* __restrict__ W_out,
    const float* __restrict__ b_out,
    float* __restrict__ out,
    int B)
{
    __shared__ __align__(16) float w_lds[NQ * HDIM];   // 4 KB  W_embed
    __shared__ float ang_lds[NQ][RPB];                 // 2 KB  angles [q][row]
    __shared__ float rot_lds[NL * NQ][8];              // Rot matrices (shared across batch)
    __shared__ float wout_lds[NA * NQ];
    __shared__ float bout_lds[NA];

    const int tid = threadIdx.x;
    const long rowBase = (long)blockIdx.x * RPB;

    // ---- stage shared weights ----
#pragma unroll
    for (int k = 0; k < 4; ++k) w_lds[tid + k * 256] = W_embed[tid + k * 256];
    if (tid < NA * NQ) wout_lds[tid] = W_out[tid];
    if (tid < NA)      bout_lds[tid] = b_out[tid];
    if (tid < NL * NQ) {
        // Rot(phi,theta,omega) = RZ(omega) RY(theta) RZ(phi)
        const float phi = q_weights[tid * 3 + 0];
        const float th  = q_weights[tid * 3 + 1];
        const float om  = q_weights[tid * 3 + 2];
        const float c  = cosf(0.5f * th), s  = sinf(0.5f * th);
        const float al = 0.5f * (phi + om), be = 0.5f * (phi - om);
        const float ca = cosf(al), sa = sinf(al);
        const float cb = cosf(be), sb = sinf(be);
        rot_lds[tid][0] =  ca * c;  rot_lds[tid][1] = -sa * c;   // u00
        rot_lds[tid][2] = -cb * s;  rot_lds[tid][3] = -sb * s;   // u01
        rot_lds[tid][4] =  cb * s;  rot_lds[tid][5] = -sb * s;   // u10
        rot_lds[tid][6] =  ca * c;  rot_lds[tid][7] =  sa * c;   // u11
    }
    __syncthreads();

    // ---- phase 1: angles = tanh(h @ W_embed^T + b_embed) ----
    // 64 groups x 4 lanes; each group owns 2 rows. h staged in registers
    // (16 outstanding float4 loads) before any FMA; W LDS reads hoisted
    // across both rows.
    const int t = tid & 3;
    const int g = tid >> 2;
    const long row0 = rowBase + g * 2;
    const long row1 = row0 + 1;
    const float be0 = b_embed[0], be1 = b_embed[1], be2 = b_embed[2], be3 = b_embed[3];

    float acc0[NQ] = {0.f, 0.f, 0.f, 0.f};
    float acc1[NQ] = {0.f, 0.f, 0.f, 0.f};

    const float4* hr0 = (const float4*)(h + row0 * (long)HDIM);
    const float4* hr1 = (const float4*)(h + row1 * (long)HDIM);

#pragma unroll
    for (int half = 0; half < 2; ++half) {
        const int jb = half * 8;
        float4 a0[8], a1[8];
        if (row0 < B) {
#pragma unroll
            for (int j = 0; j < 8; ++j) a0[j] = hr0[(jb + j) * 4 + t];
#pragma unroll
            for (int j = 0; j < 8; ++j) a1[j] = hr1[(jb + j) * 4 + t];
        } else {
#pragma unroll
            for (int j = 0; j < 8; ++j) { a0[j] = make_float4(0,0,0,0); a1[j] = a0[j]; }
        }
#pragma unroll
        for (int j = 0; j < 8; ++j) {
            const int col = (jb + j) * 16 + t * 4;
            const float4 w0 = *(const float4*)&w_lds[0 * HDIM + col];
            const float4 w1 = *(const float4*)&w_lds[1 * HDIM + col];
            const float4 w2 = *(const float4*)&w_lds[2 * HDIM + col];
            const float4 w3 = *(const float4*)&w_lds[3 * HDIM + col];
            acc0[0] = fmaf(a0[j].x, w0.x, fmaf(a0[j].y, w0.y, fmaf(a0[j].z, w0.z, fmaf(a0[j].w, w0.w, acc0[0]))));
            acc0[1] = fmaf(a0[j].x, w1.x, fmaf(a0[j].y, w1.y, fmaf(a0[j].z, w1.z, fmaf(a0[j].w, w1.w, acc0[1]))));
            acc0[2] = fmaf(a0[j].x, w2.x, fmaf(a0[j].y, w2.y, fmaf(a0[j].z, w2.z, fmaf(a0[j].w, w2.w, acc0[2]))));
            acc0[3] = fmaf(a0[j].x, w3.x, fmaf(a0[j].y, w3.y, fmaf(a0[j].z, w3.z, fmaf(a0[j].w, w3.w, acc0[3]))));
            acc1[0] = fmaf(a1[j].x, w0.x, fmaf(a1[j].y, w0.y, fmaf(a1[j].z, w0.z, fmaf(a1[j].w, w0.w, acc1[0]))));
            acc1[1] = fmaf(a1[j].x, w1.x, fmaf(a1[j].y, w1.y, fmaf(a1[j].z, w1.z, fmaf(a1[j].w, w1.w, acc1[1]))));
            acc1[2] = fmaf(a1[j].x, w2.x, fmaf(a1[j].y, w2.y, fmaf(a1[j].z, w2.z, fmaf(a1[j].w, w2.w, acc1[2]))));
            acc1[3] = fmaf(a1[j].x, w3.x, fmaf(a1[j].y, w3.y, fmaf(a1[j].z, w3.z, fmaf(a1[j].w, w3.w, acc1[3]))));
        }
    }

#pragma unroll
    for (int q = 0; q < NQ; ++q) {
        acc0[q] += __shfl_xor(acc0[q], 1); acc0[q] += __shfl_xor(acc0[q], 2);
        acc1[q] += __shfl_xor(acc1[q], 1); acc1[q] += __shfl_xor(acc1[q], 2);
    }
    if (t == 0 && row0 < B) {
        ang_lds[0][g * 2] = tanhf(acc0[0] + be0);
        ang_lds[1][g * 2] = tanhf(acc0[1] + be1);
        ang_lds[2][g * 2] = tanhf(acc0[2] + be2);
        ang_lds[3][g * 2] = tanhf(acc0[3] + be3);
        ang_lds[0][g * 2 + 1] = tanhf(acc1[0] + be0);
        ang_lds[1][g * 2 + 1] = tanhf(acc1[1] + be1);
        ang_lds[2][g * 2 + 1] = tanhf(acc1[2] + be2);
        ang_lds[3][g * 2 + 1] = tanhf(acc1[3] + be3);
    }
    __syncthreads();

    // ---- phase 2: one thread = one row (first RPB threads) ----
    const int  lrow = tid;
    const long grow = rowBase + lrow;
    if (lrow >= RPB || grow >= B) return;

    float sr[16], si[16];
#pragma unroll
    for (int k = 0; k < 16; ++k) { sr[k] = 0.f; si[k] = 0.f; }
    sr[0] = 1.0f;

    // AngleEmbedding: RX(theta_q) on qubit q
#pragma unroll
    for (int q = 0; q < NQ; ++q) {
        const float th = ang_lds[q][lrow];
        const float c = __cosf(0.5f * th), s = __sinf(0.5f * th);
        const int m = 8 >> q;
#pragma unroll
        for (int k = 0; k < 16; ++k) {
            if (k & m) continue;
            const int k1 = k | m;
            const float a0r = sr[k],  a0i = si[k];
            const float a1r = sr[k1], a1i = si[k1];
            sr[k]  = c * a0r + s * a1i;
            si[k]  = c * a0i - s * a1r;
            sr[k1] = s * a0i + c * a1r;
            si[k1] = c * a1i - s * a0r;
        }
    }

    // StronglyEntanglingLayers
    apply_u<8>(sr, si, rot_lds[0]);
    apply_u<4>(sr, si, rot_lds[1]);
    apply_u<2>(sr, si, rot_lds[2]);
    apply_u<1>(sr, si, rot_lds[3]);
    cnot<8, 4>(sr, si);
    cnot<4, 2>(sr, si);
    cnot<2, 1>(sr, si);
    cnot<1, 8>(sr, si);
    apply_u<8>(sr, si, rot_lds[4]);
    apply_u<4>(sr, si, rot_lds[5]);
    apply_u<2>(sr, si, rot_lds[6]);
    apply_u<1>(sr, si, rot_lds[7]);
    cnot<8, 2>(sr, si);
    cnot<4, 1>(sr, si);
    cnot<2, 8>(sr, si);
    cnot<1, 4>(sr, si);

    // PauliZ expectations
    float p[16];
#pragma unroll
    for (int k = 0; k < 16; ++k) p[k] = sr[k] * sr[k] + si[k] * si[k];
    float z[4];
#pragma unroll
    for (int q = 0; q < NQ; ++q) {
        const int m = 8 >> q;
        float zz = 0.f;
#pragma unroll
        for (int k = 0; k < 16; ++k) zz += (k & m) ? -p[k] : p[k];
        z[q] = zz;
    }

    // out = z @ W_out^T + b_out
    float4* out4 = (float4*)(out + grow * (long)NA);
#pragma unroll
    for (int i = 0; i < 4; ++i) {
        float o[4];
#pragma unroll
        for (int jj = 0; jj < 4; ++jj) {
            const int a = i * 4 + jj;
            float v = bout_lds[a];
#pragma unroll
            for (int q = 0; q < NQ; ++q) v = fmaf(z[q], wout_lds[a * 4 + q], v);
            o[jj] = v;
        }
        out4[i] = make_float4(o[0], o[1], o[2], o[3]);
    }
}

extern "C" void kernel_launch(void* const* d_in, const int* in_sizes, int n_in,
                              void* d_out, int out_size, void* d_ws, size_t ws_size,
                              hipStream_t stream) {
    const float* h         = (const float*)d_in[0];
    const float* W_embed   = (const float*)d_in[1];
    const float* b_embed   = (const float*)d_in[2];
    const float* q_weights = (const float*)d_in[3];
    const float* W_out     = (const float*)d_in[4];
    const float* b_out     = (const float*)d_in[5];
    float* out = (float*)d_out;

    const int B = in_sizes[0] / HDIM;
    const int blocks = (B + RPB - 1) / RPB;
    qph_kernel<<<blocks, 256, 0, stream>>>(h, W_embed, b_embed, q_weights, W_out, b_out, out, B);
}

// Round 3
// 56.708 us; speedup vs baseline: 3.0712x; 3.0712x over previous
//
#include <hip/hip_runtime.h>

#define NQ 4
#define NL 2
#define NA 16
#define HDIM 256
#define RPB 256   // rows per block

// Generic 1-qubit gate on qubit with mask M. u = {u00r,u00i,u01r,u01i,u10r,u10i,u11r,u11i}
template<int M>
__device__ __forceinline__ void apply_u(float* sr, float* si, const float* u) {
    const float u00r = u[0], u00i = u[1], u01r = u[2], u01i = u[3];
    const float u10r = u[4], u10i = u[5], u11r = u[6], u11i = u[7];
#pragma unroll
    for (int k = 0; k < 16; ++k) {
        if (k & M) continue;
        const int k1 = k | M;
        const float a0r = sr[k],  a0i = si[k];
        const float a1r = sr[k1], a1i = si[k1];
        sr[k]  = u00r*a0r - u00i*a0i + u01r*a1r - u01i*a1i;
        si[k]  = u00r*a0i + u00i*a0r + u01r*a1i + u01i*a1r;
        sr[k1] = u10r*a0r - u10i*a0i + u11r*a1r - u11i*a1i;
        si[k1] = u10r*a0i + u10i*a0r + u11r*a1i + u11i*a1r;
    }
}

template<int MC, int MT>
__device__ __forceinline__ void cnot(float* sr, float* si) {
#pragma unroll
    for (int k = 0; k < 16; ++k) {
        if ((k & MC) && !(k & MT)) {
            const int k1 = k | MT;
            float tr = sr[k]; sr[k] = sr[k1]; sr[k1] = tr;
            float ti = si[k]; si[k] = si[k1]; si[k1] = ti;
        }
    }
}

__global__ __launch_bounds__(256) void qph_kernel(
    const float* __restrict__ h,
    const float* __restrict__ W_embed,
    const float* __restrict__ b_embed,
    const float* __restrict__ q_weights,
    const float* __restrict__ W_out,
    const float* __restrict__ b_out,
    float* __restrict__ out,
    int B)
{
    __shared__ __align__(16) float w_lds[NQ * HDIM];   // 4 KB  W_embed
    __shared__ float rot_lds[NL * NQ][8];              // Rot matrices (shared across batch)
    __shared__ float wout_lds[NA * NQ];
    __shared__ float bout_lds[NA];

    const int tid = threadIdx.x;
    const long rowBase = (long)blockIdx.x * RPB;

    // ---- stage shared weights (single barrier) ----
#pragma unroll
    for (int k = 0; k < 4; ++k) w_lds[tid + k * 256] = W_embed[tid + k * 256];
    if (tid < NA * NQ) wout_lds[tid] = W_out[tid];
    if (tid < NA)      bout_lds[tid] = b_out[tid];
    if (tid < NL * NQ) {
        // Rot(phi,theta,omega) = RZ(omega) RY(theta) RZ(phi)
        const float phi = q_weights[tid * 3 + 0];
        const float th  = q_weights[tid * 3 + 1];
        const float om  = q_weights[tid * 3 + 2];
        const float c  = cosf(0.5f * th), s  = sinf(0.5f * th);
        const float al = 0.5f * (phi + om), be = 0.5f * (phi - om);
        const float ca = cosf(al), sa = sinf(al);
        const float cb = cosf(be), sb = sinf(be);
        rot_lds[tid][0] =  ca * c;  rot_lds[tid][1] = -sa * c;   // u00
        rot_lds[tid][2] = -cb * s;  rot_lds[tid][3] = -sb * s;   // u01
        rot_lds[tid][4] =  cb * s;  rot_lds[tid][5] = -sb * s;   // u10
        rot_lds[tid][6] =  ca * c;  rot_lds[tid][7] =  sa * c;   // u11
    }
    __syncthreads();

    // ---- phase 1: angles = tanh(h @ W_embed^T + b_embed), 4 lanes per row ----
    // After the 4-lane butterfly every lane holds all 4 sums; lane t keeps
    // the sums of iteration rr==t, so thread tid ends owning row rowBase+tid.
    // No LDS round-trip, no further barriers.
    const int t = tid & 3;   // lane within 4-lane group
    const int g = tid >> 2;  // group id 0..63
    const float be0 = b_embed[0], be1 = b_embed[1], be2 = b_embed[2], be3 = b_embed[3];

    float my0 = 0.f, my1 = 0.f, my2 = 0.f, my3 = 0.f;

#pragma unroll
    for (int rr = 0; rr < 4; ++rr) {
        const int  lrow = g * 4 + rr;
        const long grow = rowBase + lrow;
        float acc0 = 0.f, acc1 = 0.f, acc2 = 0.f, acc3 = 0.f;
        if (grow < B) {
            const float4* hrow = (const float4*)(h + grow * (long)HDIM);
#pragma unroll
            for (int j = 0; j < 16; ++j) {
                const float4 hv = hrow[j * 4 + t];
                const float4 w0 = *(const float4*)&w_lds[0 * HDIM + j * 16 + t * 4];
                const float4 w1 = *(const float4*)&w_lds[1 * HDIM + j * 16 + t * 4];
                const float4 w2 = *(const float4*)&w_lds[2 * HDIM + j * 16 + t * 4];
                const float4 w3 = *(const float4*)&w_lds[3 * HDIM + j * 16 + t * 4];
                acc0 = fmaf(hv.x, w0.x, fmaf(hv.y, w0.y, fmaf(hv.z, w0.z, fmaf(hv.w, w0.w, acc0))));
                acc1 = fmaf(hv.x, w1.x, fmaf(hv.y, w1.y, fmaf(hv.z, w1.z, fmaf(hv.w, w1.w, acc1))));
                acc2 = fmaf(hv.x, w2.x, fmaf(hv.y, w2.y, fmaf(hv.z, w2.z, fmaf(hv.w, w2.w, acc2))));
                acc3 = fmaf(hv.x, w3.x, fmaf(hv.y, w3.y, fmaf(hv.z, w3.z, fmaf(hv.w, w3.w, acc3))));
            }
        }
        // reduce across the 4 lanes of the group (butterfly) -> all lanes hold sums
        acc0 += __shfl_xor(acc0, 1); acc0 += __shfl_xor(acc0, 2);
        acc1 += __shfl_xor(acc1, 1); acc1 += __shfl_xor(acc1, 2);
        acc2 += __shfl_xor(acc2, 1); acc2 += __shfl_xor(acc2, 2);
        acc3 += __shfl_xor(acc3, 1); acc3 += __shfl_xor(acc3, 2);
        if (t == rr) { my0 = acc0; my1 = acc1; my2 = acc2; my3 = acc3; }
    }

    // ---- phase 2: this thread owns row rowBase + tid ----
    const long grow = rowBase + tid;
    if (grow >= B) return;

    const float ang0 = tanhf(my0 + be0);
    const float ang1 = tanhf(my1 + be1);
    const float ang2 = tanhf(my2 + be2);
    const float ang3 = tanhf(my3 + be3);

    float sr[16], si[16];
#pragma unroll
    for (int k = 0; k < 16; ++k) { sr[k] = 0.f; si[k] = 0.f; }
    sr[0] = 1.0f;

    // AngleEmbedding: RX(theta_q) on qubit q
    const float angs[4] = {ang0, ang1, ang2, ang3};
#pragma unroll
    for (int q = 0; q < NQ; ++q) {
        const float th = angs[q];
        const float c = __cosf(0.5f * th), s = __sinf(0.5f * th);
        const int m = 8 >> q;
#pragma unroll
        for (int k = 0; k < 16; ++k) {
            if (k & m) continue;
            const int k1 = k | m;
            const float a0r = sr[k],  a0i = si[k];
            const float a1r = sr[k1], a1i = si[k1];
            sr[k]  = c * a0r + s * a1i;
            si[k]  = c * a0i - s * a1r;
            sr[k1] = s * a0i + c * a1r;
            si[k1] = c * a1i - s * a0r;
        }
    }

    // StronglyEntanglingLayers
    apply_u<8>(sr, si, rot_lds[0]);
    apply_u<4>(sr, si, rot_lds[1]);
    apply_u<2>(sr, si, rot_lds[2]);
    apply_u<1>(sr, si, rot_lds[3]);
    cnot<8, 4>(sr, si);
    cnot<4, 2>(sr, si);
    cnot<2, 1>(sr, si);
    cnot<1, 8>(sr, si);
    apply_u<8>(sr, si, rot_lds[4]);
    apply_u<4>(sr, si, rot_lds[5]);
    apply_u<2>(sr, si, rot_lds[6]);
    apply_u<1>(sr, si, rot_lds[7]);
    cnot<8, 2>(sr, si);
    cnot<4, 1>(sr, si);
    cnot<2, 8>(sr, si);
    cnot<1, 4>(sr, si);

    // PauliZ expectations
    float p[16];
#pragma unroll
    for (int k = 0; k < 16; ++k) p[k] = sr[k] * sr[k] + si[k] * si[k];
    float z[4];
#pragma unroll
    for (int q = 0; q < NQ; ++q) {
        const int m = 8 >> q;
        float zz = 0.f;
#pragma unroll
        for (int k = 0; k < 16; ++k) zz += (k & m) ? -p[k] : p[k];
        z[q] = zz;
    }

    // out = z @ W_out^T + b_out
    float4* out4 = (float4*)(out + grow * (long)NA);
#pragma unroll
    for (int i = 0; i < 4; ++i) {
        float o[4];
#pragma unroll
        for (int jj = 0; jj < 4; ++jj) {
            const int a = i * 4 + jj;
            float v = bout_lds[a];
#pragma unroll
            for (int q = 0; q < NQ; ++q) v = fmaf(z[q], wout_lds[a * 4 + q], v);
            o[jj] = v;
        }
        out4[i] = make_float4(o[0], o[1], o[2], o[3]);
    }
}

extern "C" void kernel_launch(void* const* d_in, const int* in_sizes, int n_in,
                              void* d_out, int out_size, void* d_ws, size_t ws_size,
                              hipStream_t stream) {
    const float* h         = (const float*)d_in[0];
    const float* W_embed   = (const float*)d_in[1];
    const float* b_embed   = (const float*)d_in[2];
    const float* q_weights = (const float*)d_in[3];
    const float* W_out     = (const float*)d_in[4];
    const float* b_out     = (const float*)d_in[5];
    float* out = (float*)d_out;

    const int B = in_sizes[0] / HDIM;
    const int blocks = (B + RPB - 1) / RPB;
    qph_kernel<<<blocks, 256, 0, stream>>>(h, W_embed, b_embed, q_weights, W_out, b_out, out, B);
}